// Round 1
// baseline (48.898 us; speedup 1.0000x reference)
//
#include <hip/hip_runtime.h>

// Round 1: coalesced float4 quad-per-row kernel + deterministic 2-pass reduction.
// Memory-bound: 256 MiB read -> ~43us roofline at 6.3 TB/s.

__global__ __launch_bounds__(256) void mse2_partial(
    const float4* __restrict__ O4, const float4* __restrict__ L4,
    float* __restrict__ partial, int n4)
{
    const int tid    = blockIdx.x * blockDim.x + threadIdx.x;
    const int stride = gridDim.x * blockDim.x;
    const int q  = threadIdx.x & 3;      // quad lane: which float4 of the row
    const int c0 = q * 4;                // first column this lane owns

    float acc = 0.0f;

    for (int g = tid; g < n4; g += stride) {
        // g = row*4 + q ; consecutive lanes -> consecutive float4 elements (coalesced)
        float4 l = L4[g];
        float4 o = O4[g];

        // lab0 lives in lane q==0 of each quad (l.x). Broadcast within the quad.
        float lab0 = __shfl(l.x, 0, 4);

        // r = round-half-even(3*lab0); n per reference nesting
        int r = (int)rintf(3.0f * lab0);
        int n = (lab0 == 0.0f) ? 1
              : (r == 1 ? 3 : (r == 2 ? 6 : (r == 3 ? 9 : 0)));

        float dx = o.x - l.x;
        float dy = o.y - l.y;
        float dz = o.z - l.z;
        float dw = o.w - l.w;

        float s = 0.0f;
        if (c0 + 0 < n) s += dx * dx;
        if (c0 + 1 < n) s += dy * dy;
        if (c0 + 2 < n) s += dz * dz;
        if (c0 + 3 < n) s += dw * dw;

        // quad reduction: all 4 lanes end with the row's masked sum
        s += __shfl_xor(s, 1, 4);
        s += __shfl_xor(s, 2, 4);

        if (q == 0 && n > 0) acc += s / (float)n;
    }

    // wave64 reduction
    #pragma unroll
    for (int off = 32; off >= 1; off >>= 1)
        acc += __shfl_down(acc, off, 64);

    __shared__ float red[4];
    const int wave = threadIdx.x >> 6;
    if ((threadIdx.x & 63) == 0) red[wave] = acc;
    __syncthreads();

    if (threadIdx.x == 0)
        partial[blockIdx.x] = red[0] + red[1] + red[2] + red[3];
}

__global__ __launch_bounds__(256) void mse2_final(
    const float* __restrict__ partial, int nb,
    float* __restrict__ out, float inv_b)
{
    float acc = 0.0f;
    for (int i = threadIdx.x; i < nb; i += blockDim.x)
        acc += partial[i];

    #pragma unroll
    for (int off = 32; off >= 1; off >>= 1)
        acc += __shfl_down(acc, off, 64);

    __shared__ float red[4];
    const int wave = threadIdx.x >> 6;
    if ((threadIdx.x & 63) == 0) red[wave] = acc;
    __syncthreads();

    if (threadIdx.x == 0)
        out[0] = (red[0] + red[1] + red[2] + red[3]) * inv_b;
}

extern "C" void kernel_launch(void* const* d_in, const int* in_sizes, int n_in,
                              void* d_out, int out_size, void* d_ws, size_t ws_size,
                              hipStream_t stream) {
    const float* outputs = (const float*)d_in[0];
    const float* labels  = (const float*)d_in[1];

    const int total = in_sizes[0];   // B * 16
    const int n4    = total / 4;     // number of float4 elements
    const int b     = total / 16;    // number of rows

    int threads = 256;
    int blocks  = 2048;              // memory-bound: ~2k blocks, grid-stride
    // keep one float partial per block in d_ws
    int max_blocks = (int)(ws_size / sizeof(float));
    if (max_blocks < 1) max_blocks = 1;
    if (blocks > max_blocks) blocks = max_blocks;

    float* partial = (float*)d_ws;

    mse2_partial<<<blocks, threads, 0, stream>>>(
        (const float4*)outputs, (const float4*)labels, partial, n4);
    mse2_final<<<1, 256, 0, stream>>>(
        partial, blocks, (float*)d_out, 1.0f / (float)b);
}